// Round 1
// baseline (1187.693 us; speedup 1.0000x reference)
//
#include <hip/hip_runtime.h>
#include <hip/hip_bf16.h>
#include <math.h>

// ---------- constants ----------
#define Bsz 4
#define Cin 512
#define Hh 16
#define Ww 16
#define Lsp 256
#define DIM 128
#define DM 1024      // dim*4 + 512
#define DI 2048
#define KK 4
#define NST 16
#define RR 64

// ---------- ws layout (floats) ----------
#define OFF_FEAT    0u
#define SZ_FEAT     (Bsz*Lsp*DM)                 // 1048576
#define OFF_POOLED  (OFF_FEAT + SZ_FEAT)
#define SZ_POOLED   (Bsz*Cin*275)                // 563200
#define OFF_PCONV   (OFF_POOLED + SZ_POOLED)
#define SZ_PCONV    (Bsz*275*DIM)                // 140800
#define OFF_Y0M     (OFF_PCONV + SZ_PCONV)
#define SZ_Y0M      (Bsz*DIM)                    // 512
#define OFF_XZ      (OFF_Y0M + SZ_Y0M)
#define SZ_XZ       (Bsz*Lsp*2*DI)               // 4194304
#define OFF_XCT     (OFF_XZ + SZ_XZ)
#define SZ_XCT      (Bsz*Lsp*DI)                 // 2097152
#define OFF_XDBL    (OFF_XCT + SZ_XCT)
#define SZ_XDBL     (Bsz*KK*96*Lsp)              // 393216
#define OFF_DELTA   (OFF_XDBL + SZ_XDBL)
#define SZ_DELTA    (Bsz*KK*Lsp*DI)              // 8388608
#define OFF_OUTY    (OFF_DELTA + SZ_DELTA)
#define SZ_OUTY     (Bsz*KK*Lsp*DI)              // 8388608
#define OFF_YG      (OFF_OUTY + SZ_OUTY)
#define SZ_YG       (Bsz*Lsp*DI)                 // 2097152
#define OFF_O1      (OFF_YG + SZ_YG)
#define SZ_O1       (Bsz*Lsp*DM)                 // 1048576
#define OFF_O2      (OFF_O1 + SZ_O1)
#define SZ_O2       (Bsz*Lsp*DIM)                // 131072
#define WS_FLOATS   (OFF_O2 + SZ_O2)             // 28491776 floats = ~108.7 MiB

// ---------- pool layer 0: conv1x1+BN+ReLU then global mean ----------
__global__ __launch_bounds__(256) void pool0_kernel(
    const float* __restrict__ x, const float* __restrict__ pw, const float* __restrict__ pb,
    const float* __restrict__ g, const float* __restrict__ bb,
    const float* __restrict__ m, const float* __restrict__ v, float* __restrict__ y0m) {
  int bd = blockIdx.x;             // b*128+d
  int b = bd >> 7, d = bd & 127;
  int l = threadIdx.x;
  const float* xb = x + (b*Cin)*Lsp + l;
  const float* w = pw + d*Cin;     // layer 0
  float s = 0.f;
  #pragma unroll 4
  for (int c = 0; c < Cin; ++c) s += xb[c*Lsp] * w[c];
  s += pb[d];
  float inv = g[d] * rsqrtf(v[d] + 1e-5f);
  s = s*inv + (bb[d] - m[d]*inv);
  s = fmaxf(s, 0.f);
  __shared__ float red[256];
  red[l] = s; __syncthreads();
  for (int off = 128; off > 0; off >>= 1) {
    if (l < off) red[l] += red[l+off];
    __syncthreads();
  }
  if (l == 0) y0m[bd] = red[0] * (1.f/256.f);
}

// ---------- adaptive avg pool of x to 5x5,9x9,13x13 (concatenated 275 positions) ----------
__device__ __forceinline__ void decode_pos(int pos, int& s, int& pp, int& qq, int& layer) {
  if (pos < 25)       { s = 5;  layer = 1; int t = pos;       pp = t/5;  qq = t%5;  }
  else if (pos < 106) { s = 9;  layer = 2; int t = pos - 25;  pp = t/9;  qq = t%9;  }
  else                { s = 13; layer = 3; int t = pos - 106; pp = t/13; qq = t%13; }
}

__global__ void pool_avg_kernel(const float* __restrict__ x, float* __restrict__ pooled) {
  int bc = blockIdx.x;             // b*512+c
  int pos = threadIdx.x;
  if (pos >= 275) return;
  int s, pp, qq, layer;
  decode_pos(pos, s, pp, qq, layer);
  int hs = (pp*Hh)/s, he = ((pp+1)*Hh + s-1)/s;
  int ws = (qq*Ww)/s, we = ((qq+1)*Ww + s-1)/s;
  const float* xb = x + bc*Lsp;
  float acc = 0.f;
  for (int hh = hs; hh < he; ++hh)
    for (int ww2 = ws; ww2 < we; ++ww2)
      acc += xb[hh*Ww + ww2];
  pooled[bc*275 + pos] = acc / (float)((he-hs)*(we-ws));
}

// ---------- conv1x1 + BN + ReLU on pooled features ----------
__global__ void pconv_kernel(const float* __restrict__ pooled, const float* __restrict__ pw,
    const float* __restrict__ pb, const float* __restrict__ g, const float* __restrict__ bb,
    const float* __restrict__ m, const float* __restrict__ v, float* __restrict__ pconv) {
  int bp = blockIdx.x;             // b*275+pos
  int b = bp / 275, pos = bp % 275;
  int d = threadIdx.x;             // 0..127
  int s, pp, qq, layer;
  decode_pos(pos, s, pp, qq, layer);
  const float* pc = pooled + b*Cin*275 + pos;
  const float* w = pw + (layer*DIM + d)*Cin;
  float acc = 0.f;
  #pragma unroll 4
  for (int c = 0; c < Cin; ++c) acc += pc[c*275] * w[c];
  acc += pb[layer*DIM + d];
  int ld = layer*DIM + d;
  float inv = g[ld] * rsqrtf(v[ld] + 1e-5f);
  acc = acc*inv + (bb[ld] - m[ld]*inv);
  pconv[bp*DIM + d] = fmaxf(acc, 0.f);
}

// ---------- assemble feat (B,L,1024): [x | broadcast(y0) | up5 | up9 | up13] ----------
__global__ __launch_bounds__(256) void feat_kernel(const float* __restrict__ x,
    const float* __restrict__ y0m, const float* __restrict__ pconv, float* __restrict__ feat) {
  int bl = blockIdx.x;             // b*256+l
  int b = bl >> 8, l = bl & 255;
  int h = l >> 4, w = l & 15;
  for (int c = threadIdx.x; c < DM; c += 256) {
    float val;
    if (c < Cin) {
      val = x[(b*Cin + c)*Lsp + l];
    } else if (c < Cin + DIM) {
      val = y0m[b*DIM + (c - Cin)];
    } else {
      int i = (c - (Cin+DIM)) >> 7;          // 0,1,2 -> s=5,9,13
      int d = (c - (Cin+DIM)) & 127;
      int s = (i==0) ? 5 : (i==1) ? 9 : 13;
      int off = (i==0) ? 0 : (i==1) ? 25 : 106;
      float scale = (float)s / 16.f;
      float sh = fmaxf((h + 0.5f)*scale - 0.5f, 0.f);
      int h0 = min((int)sh, s-1); float wh = sh - (float)h0; int h1 = min(h0+1, s-1);
      float sw = fmaxf((w + 0.5f)*scale - 0.5f, 0.f);
      int w0 = min((int)sw, s-1); float ww2 = sw - (float)w0; int w1 = min(w0+1, s-1);
      const float* pc = pconv + b*275*DIM;
      float v00 = pc[(off + h0*s + w0)*DIM + d];
      float v01 = pc[(off + h0*s + w1)*DIM + d];
      float v10 = pc[(off + h1*s + w0)*DIM + d];
      float v11 = pc[(off + h1*s + w1)*DIM + d];
      val = (1.f-wh)*((1.f-ww2)*v00 + ww2*v01) + wh*((1.f-ww2)*v10 + ww2*v11);
    }
    feat[bl*DM + c] = val;
  }
}

// ---------- generic fp32 GEMM: C[M][N] = A[M][Kd] * B[N][Kd]^T ----------
#define TS 64
#define KT 16
__global__ __launch_bounds__(256) void gemm_nt(const float* __restrict__ A,
    const float* __restrict__ B, float* __restrict__ C, int M, int N, int Kd) {
  __shared__ float As[KT][TS+1];
  __shared__ float Bs[KT][TS+1];
  int tid = threadIdx.x;
  int col0 = blockIdx.x * TS;
  int row0 = blockIdx.y * TS;
  int tx = tid & 15, ty = tid >> 4;
  float acc[4][4] = {};
  for (int k0 = 0; k0 < Kd; k0 += KT) {
    #pragma unroll
    for (int i = 0; i < 4; ++i) {
      int e = tid + 256*i;
      int r = e >> 4, kk = e & 15;
      As[kk][r] = A[(row0 + r)*Kd + k0 + kk];
      Bs[kk][r] = B[(col0 + r)*Kd + k0 + kk];
    }
    __syncthreads();
    #pragma unroll
    for (int kk = 0; kk < KT; ++kk) {
      float a[4], bvr[4];
      #pragma unroll
      for (int i = 0; i < 4; ++i) a[i] = As[kk][ty*4+i];
      #pragma unroll
      for (int j = 0; j < 4; ++j) bvr[j] = Bs[kk][tx*4+j];
      #pragma unroll
      for (int i = 0; i < 4; ++i)
        #pragma unroll
        for (int j = 0; j < 4; ++j)
          acc[i][j] += a[i]*bvr[j];
    }
    __syncthreads();
  }
  #pragma unroll
  for (int i = 0; i < 4; ++i)
    #pragma unroll
    for (int j = 0; j < 4; ++j)
      C[(row0 + ty*4 + i)*N + col0 + tx*4 + j] = acc[i][j];
}

// ---------- depthwise 3x3 conv + bias + silu; xz(B,L,4096) first half -> xcT(B,L,2048) ----------
__global__ __launch_bounds__(256) void dwconv_kernel(const float* __restrict__ xz,
    const float* __restrict__ cw, const float* __restrict__ cb, float* __restrict__ xcT) {
  int bl = blockIdx.x;
  int b = bl >> 8, l = bl & 255;
  int h = l >> 4, w = l & 15;
  const float* xzb = xz + (size_t)b*Lsp*(2*DI);
  for (int d = threadIdx.x; d < DI; d += 256) {
    float s = 0.f;
    #pragma unroll
    for (int dh = -1; dh <= 1; ++dh) {
      int hh = h + dh; if (hh < 0 || hh > 15) continue;
      #pragma unroll
      for (int dw = -1; dw <= 1; ++dw) {
        int ww2 = w + dw; if (ww2 < 0 || ww2 > 15) continue;
        s += xzb[(hh*16 + ww2)*(2*DI) + d] * cw[d*9 + (dh+1)*3 + (dw+1)];
      }
    }
    s += cb[d];
    xcT[((size_t)b*Lsp + l)*DI + d] = s / (1.f + __expf(-s));   // silu
  }
}

// scan-direction spatial index map
__device__ __forceinline__ int dir_map(int k, int l) {
  if (k == 0) return l;
  if (k == 1) return ((l & 15) << 4) | (l >> 4);
  if (k == 2) return 255 - l;
  int m = 255 - l; return ((m & 15) << 4) | (m >> 4);
}

// ---------- x_dbl[b,k,c,l] = sum_d xs4[b,k,d,l] * x_proj_w[k,c,d] ----------
__global__ void xproj_kernel(const float* __restrict__ xcT, const float* __restrict__ xpw,
    float* __restrict__ x_dbl) {
  int bk = blockIdx.x;             // b*4+k
  int b = bk >> 2, k = bk & 3;
  int c = blockIdx.y*4 + threadIdx.y;
  int l = blockIdx.z*64 + threadIdx.x;
  int sp = dir_map(k, l);
  const float* xr = xcT + ((size_t)b*Lsp + sp)*DI;
  const float* wr = xpw + ((size_t)k*96 + c)*DI;
  float s0=0.f, s1=0.f, s2=0.f, s3=0.f;
  for (int d = 0; d < DI; d += 4) {
    s0 += xr[d  ]*wr[d  ];
    s1 += xr[d+1]*wr[d+1];
    s2 += xr[d+2]*wr[d+2];
    s3 += xr[d+3]*wr[d+3];
  }
  x_dbl[((size_t)bk*96 + c)*Lsp + l] = (s0+s1)+(s2+s3);
}

// ---------- delta[b,k,l,d] = softplus(sum_r dts[b,k,r,l]*dt_w[k,d,r] + dt_b[k,d]) ----------
__global__ __launch_bounds__(256) void delta_kernel(const float* __restrict__ x_dbl,
    const float* __restrict__ dtw, const float* __restrict__ dtb, float* __restrict__ delta) {
  int bk = blockIdx.x;             // b*4+k
  int k = bk & 3;
  int d = blockIdx.y*256 + threadIdx.x;
  int l0 = blockIdx.z*64;
  const float* wr = dtw + ((size_t)k*DI + d)*RR;
  float w[RR];
  #pragma unroll
  for (int r = 0; r < RR; ++r) w[r] = wr[r];
  float bias = dtb[k*DI + d];
  const float* dts = x_dbl + (size_t)bk*96*Lsp;   // [r][l]
  float* out = delta + (size_t)bk*Lsp*DI;
  for (int l = l0; l < l0 + 64; ++l) {
    float s = bias;
    #pragma unroll
    for (int r = 0; r < RR; ++r) s += dts[r*Lsp + l] * w[r];
    out[l*DI + d] = (s > 20.f) ? s : log1pf(__expf(s));
  }
}

// ---------- selective scan: thread per (b,k,d), h[16] in registers ----------
__global__ __launch_bounds__(256) void scan_kernel(const float* __restrict__ delta,
    const float* __restrict__ xcT, const float* __restrict__ x_dbl,
    const float* __restrict__ A_logs, const float* __restrict__ Ds, float* __restrict__ out_y) {
  int bk = blockIdx.x;             // b*4+k
  int b = bk >> 2, k = bk & 3;
  int d = blockIdx.y*256 + threadIdx.x;
  float A[NST], h[NST];
  #pragma unroll
  for (int n = 0; n < NST; ++n) {
    A[n] = -__expf(A_logs[((size_t)k*DI + d)*NST + n]);
    h[n] = 0.f;
  }
  float Dv = Ds[k*DI + d];
  const float* del = delta + (size_t)bk*Lsp*DI;
  const float* xb  = x_dbl + (size_t)bk*96*Lsp;
  const float* xc  = xcT + (size_t)b*Lsp*DI;
  float* oy = out_y + (size_t)bk*Lsp*DI;
  for (int l = 0; l < Lsp; ++l) {
    int sp = dir_map(k, l);
    float dl = del[l*DI + d];
    float ul = xc[sp*DI + d];
    float du = dl * ul;
    float y = 0.f;
    #pragma unroll
    for (int n = 0; n < NST; ++n) {
      float Bn = xb[(RR + n)*Lsp + l];
      float Cn = xb[(RR + NST + n)*Lsp + l];
      h[n] = h[n]*__expf(dl*A[n]) + du*Bn;
      y += h[n]*Cn;
    }
    oy[l*DI + d] = y + Dv*ul;
  }
}

// ---------- combine 4 directions + LayerNorm + gate with silu(z) ----------
__global__ __launch_bounds__(256) void combine_ln_kernel(const float* __restrict__ out_y,
    const float* __restrict__ xz, const float* __restrict__ lng, const float* __restrict__ lnb,
    float* __restrict__ yg) {
  int bl = blockIdx.x;
  int b = bl >> 8, l = bl & 255;
  int h = l >> 4, w = l & 15;
  int lT = (w << 4) | h;
  const float* oy = out_y + (size_t)b*KK*Lsp*DI;
  float vals[8];
  float sum = 0.f, sumsq = 0.f;
  #pragma unroll
  for (int i = 0; i < 8; ++i) {
    int d = threadIdx.x + i*256;
    float yv = oy[(0*Lsp + l       )*DI + d]
             + oy[(2*Lsp + (255-l ))*DI + d]
             + oy[(1*Lsp + lT      )*DI + d]
             + oy[(3*Lsp + (255-lT))*DI + d];
    vals[i] = yv; sum += yv; sumsq += yv*yv;
  }
  __shared__ float r1[256], r2[256];
  r1[threadIdx.x] = sum; r2[threadIdx.x] = sumsq; __syncthreads();
  for (int off = 128; off > 0; off >>= 1) {
    if (threadIdx.x < off) { r1[threadIdx.x] += r1[threadIdx.x+off]; r2[threadIdx.x] += r2[threadIdx.x+off]; }
    __syncthreads();
  }
  float mu = r1[0] * (1.f/2048.f);
  float var = r2[0] * (1.f/2048.f) - mu*mu;
  float rstd = rsqrtf(var + 1e-5f);
  const float* zrow = xz + (size_t)bl*(2*DI) + DI;
  #pragma unroll
  for (int i = 0; i < 8; ++i) {
    int d = threadIdx.x + i*256;
    float z = zrow[d];
    float sz = z / (1.f + __expf(-z));
    yg[(size_t)bl*DI + d] = ((vals[i]-mu)*rstd*lng[d] + lnb[d]) * sz;
  }
}

// ---------- cbr epilogue: bias + BN + exact GELU, write NCHW ----------
__global__ void cbr_epilogue(const float* __restrict__ o2, const float* __restrict__ cb,
    const float* __restrict__ g, const float* __restrict__ beta, const float* __restrict__ m_,
    const float* __restrict__ v_, float* __restrict__ out) {
  int idx = blockIdx.x*256 + threadIdx.x;   // (b*128+dd)*256 + l
  int l = idx & 255;
  int rest = idx >> 8;
  int dd = rest & 127;
  int b = rest >> 7;
  float s = o2[((size_t)b*Lsp + l)*DIM + dd] + cb[dd];
  float inv = g[dd] * rsqrtf(v_[dd] + 1e-5f);
  s = s*inv + (beta[dd] - m_[dd]*inv);
  out[idx] = s * 0.5f * (1.f + erff(s * 0.70710678118f));
}

extern "C" void kernel_launch(void* const* d_in, const int* in_sizes, int n_in,
                              void* d_out, int out_size, void* d_ws, size_t ws_size,
                              hipStream_t stream) {
  const float* x        = (const float*)d_in[0];
  const float* pool_w   = (const float*)d_in[1];
  const float* pool_b   = (const float*)d_in[2];
  const float* bn_g     = (const float*)d_in[3];
  const float* bn_b     = (const float*)d_in[4];
  const float* bn_m     = (const float*)d_in[5];
  const float* bn_v     = (const float*)d_in[6];
  const float* in_proj_w= (const float*)d_in[7];
  const float* conv_w   = (const float*)d_in[8];
  const float* conv_b   = (const float*)d_in[9];
  const float* x_proj_w = (const float*)d_in[10];
  const float* dt_w     = (const float*)d_in[11];
  const float* dt_b     = (const float*)d_in[12];
  const float* A_logs   = (const float*)d_in[13];
  const float* Ds       = (const float*)d_in[14];
  const float* ln_g     = (const float*)d_in[15];
  const float* ln_b     = (const float*)d_in[16];
  const float* out_proj_w=(const float*)d_in[17];
  const float* cbr_w    = (const float*)d_in[18];
  const float* cbr_b    = (const float*)d_in[19];
  const float* cbr_g    = (const float*)d_in[20];
  const float* cbr_beta = (const float*)d_in[21];
  const float* cbr_m    = (const float*)d_in[22];
  const float* cbr_v    = (const float*)d_in[23];
  float* out = (float*)d_out;

  if (ws_size < (size_t)WS_FLOATS * sizeof(float)) return;  // not enough scratch
  float* ws = (float*)d_ws;
  float* feat   = ws + OFF_FEAT;
  float* pooled = ws + OFF_POOLED;
  float* pconv  = ws + OFF_PCONV;
  float* y0m    = ws + OFF_Y0M;
  float* xz     = ws + OFF_XZ;
  float* xcT    = ws + OFF_XCT;
  float* x_dbl  = ws + OFF_XDBL;
  float* delta  = ws + OFF_DELTA;
  float* out_y  = ws + OFF_OUTY;
  float* yg     = ws + OFF_YG;
  float* o1     = ws + OFF_O1;
  float* o2     = ws + OFF_O2;

  // stage A: pyramid pooling
  pool0_kernel<<<Bsz*DIM, 256, 0, stream>>>(x, pool_w, pool_b, bn_g, bn_b, bn_m, bn_v, y0m);
  pool_avg_kernel<<<Bsz*Cin, 288, 0, stream>>>(x, pooled);
  pconv_kernel<<<Bsz*275, 128, 0, stream>>>(pooled, pool_w, pool_b, bn_g, bn_b, bn_m, bn_v, pconv);
  feat_kernel<<<Bsz*Lsp, 256, 0, stream>>>(x, y0m, pconv, feat);

  // stage B: in_proj GEMM  (M=1024, N=4096, K=1024)
  gemm_nt<<<dim3(4096/TS, 1024/TS), 256, 0, stream>>>(feat, in_proj_w, xz, 1024, 4096, 1024);

  // stage C: depthwise conv + silu
  dwconv_kernel<<<Bsz*Lsp, 256, 0, stream>>>(xz, conv_w, conv_b, xcT);

  // stage D: x_proj (B,K,96,L)
  xproj_kernel<<<dim3(Bsz*KK, 96/4, Lsp/64), dim3(64,4), 0, stream>>>(xcT, x_proj_w, x_dbl);

  // stage E: delta
  delta_kernel<<<dim3(Bsz*KK, DI/256, 4), 256, 0, stream>>>(x_dbl, dt_w, dt_b, delta);

  // stage F: selective scan
  scan_kernel<<<dim3(Bsz*KK, DI/256), 256, 0, stream>>>(delta, xcT, x_dbl, A_logs, Ds, out_y);

  // stage G: combine + LN + gate
  combine_ln_kernel<<<Bsz*Lsp, 256, 0, stream>>>(out_y, xz, ln_g, ln_b, yg);

  // stage H: out_proj GEMM (M=1024, N=1024, K=2048)
  gemm_nt<<<dim3(1024/TS, 1024/TS), 256, 0, stream>>>(yg, out_proj_w, o1, 1024, 1024, 2048);

  // stage I: cbr GEMM (M=1024, N=128, K=1024) + epilogue
  gemm_nt<<<dim3(DIM/TS, 1024/TS), 256, 0, stream>>>(o1, cbr_w, o2, 1024, DIM, 1024);
  cbr_epilogue<<<(Bsz*DIM*Lsp)/256, 256, 0, stream>>>(o2, cbr_b, cbr_g, cbr_beta, cbr_m, cbr_v, out);
}

// Round 2
// 890.899 us; speedup vs baseline: 1.3331x; 1.3331x over previous
//
#include <hip/hip_runtime.h>
#include <hip/hip_bf16.h>
#include <math.h>

// ---------- constants ----------
#define Bsz 4
#define Cin 512
#define Hh 16
#define Ww 16
#define Lsp 256
#define DIM 128
#define DM 1024      // dim*4 + 512
#define DI 2048
#define KK 4
#define NST 16
#define RR 64
#define PW 384       // K*96 projection rows

// ---------- ws layout (floats) ----------
#define OFF_FEAT    0u
#define SZ_FEAT     (Bsz*Lsp*DM)                 // 1048576
#define OFF_POOLED  (OFF_FEAT + SZ_FEAT)
#define SZ_POOLED   (Bsz*Cin*275)                // 563200
#define OFF_PCONV   (OFF_POOLED + SZ_POOLED)
#define SZ_PCONV    (Bsz*275*DIM)                // 140800
#define OFF_Y0M     (OFF_PCONV + SZ_PCONV)
#define SZ_Y0M      (Bsz*DIM)                    // 512
#define OFF_XZ      (OFF_Y0M + SZ_Y0M)
#define SZ_XZ       (Bsz*Lsp*2*DI)               // 4194304
#define OFF_XCT     (OFF_XZ + SZ_XZ)
#define SZ_XCT      (Bsz*Lsp*DI)                 // 2097152
#define OFF_XDBL    (OFF_XCT + SZ_XCT)
#define SZ_XDBL     (Bsz*Lsp*PW)                 // 393216  (P matrix, 1024x384)
#define OFF_DELTA   (OFF_XDBL + SZ_XDBL)
#define SZ_DELTA    (Bsz*KK*Lsp*DI)              // 8388608
#define OFF_OUTY    (OFF_DELTA + SZ_DELTA)
#define SZ_OUTY     (Bsz*KK*Lsp*DI)              // 8388608
#define OFF_YG      (OFF_OUTY + SZ_OUTY)
#define SZ_YG       (Bsz*Lsp*DI)                 // 2097152
#define OFF_O1      (OFF_YG + SZ_YG)
#define SZ_O1       (Bsz*Lsp*DM)                 // 1048576
#define OFF_O2      (OFF_O1 + SZ_O1)
#define SZ_O2       (Bsz*Lsp*DIM)                // 131072
#define WS_FLOATS   (OFF_O2 + SZ_O2)

// ---------- pool layer 0: conv1x1+BN+ReLU then global mean ----------
__global__ __launch_bounds__(256) void pool0_kernel(
    const float* __restrict__ x, const float* __restrict__ pw, const float* __restrict__ pb,
    const float* __restrict__ g, const float* __restrict__ bb,
    const float* __restrict__ m, const float* __restrict__ v, float* __restrict__ y0m) {
  int bd = blockIdx.x;             // b*128+d
  int b = bd >> 7, d = bd & 127;
  int l = threadIdx.x;
  const float* xb = x + (b*Cin)*Lsp + l;
  const float* w = pw + d*Cin;     // layer 0
  float s = 0.f;
  #pragma unroll 4
  for (int c = 0; c < Cin; ++c) s += xb[c*Lsp] * w[c];
  s += pb[d];
  float inv = g[d] * rsqrtf(v[d] + 1e-5f);
  s = s*inv + (bb[d] - m[d]*inv);
  s = fmaxf(s, 0.f);
  __shared__ float red[256];
  red[l] = s; __syncthreads();
  for (int off = 128; off > 0; off >>= 1) {
    if (l < off) red[l] += red[l+off];
    __syncthreads();
  }
  if (l == 0) y0m[bd] = red[0] * (1.f/256.f);
}

// ---------- adaptive avg pool of x to 5x5,9x9,13x13 (concatenated 275 positions) ----------
__device__ __forceinline__ void decode_pos(int pos, int& s, int& pp, int& qq, int& layer) {
  if (pos < 25)       { s = 5;  layer = 1; int t = pos;       pp = t/5;  qq = t%5;  }
  else if (pos < 106) { s = 9;  layer = 2; int t = pos - 25;  pp = t/9;  qq = t%9;  }
  else                { s = 13; layer = 3; int t = pos - 106; pp = t/13; qq = t%13; }
}

__global__ void pool_avg_kernel(const float* __restrict__ x, float* __restrict__ pooled) {
  int bc = blockIdx.x;             // b*512+c
  int pos = threadIdx.x;
  if (pos >= 275) return;
  int s, pp, qq, layer;
  decode_pos(pos, s, pp, qq, layer);
  int hs = (pp*Hh)/s, he = ((pp+1)*Hh + s-1)/s;
  int ws = (qq*Ww)/s, we = ((qq+1)*Ww + s-1)/s;
  const float* xb = x + bc*Lsp;
  float acc = 0.f;
  for (int hh = hs; hh < he; ++hh)
    for (int ww2 = ws; ww2 < we; ++ww2)
      acc += xb[hh*Ww + ww2];
  pooled[bc*275 + pos] = acc / (float)((he-hs)*(we-ws));
}

// ---------- conv1x1 + BN + ReLU on pooled features ----------
__global__ void pconv_kernel(const float* __restrict__ pooled, const float* __restrict__ pw,
    const float* __restrict__ pb, const float* __restrict__ g, const float* __restrict__ bb,
    const float* __restrict__ m, const float* __restrict__ v, float* __restrict__ pconv) {
  int bp = blockIdx.x;             // b*275+pos
  int b = bp / 275, pos = bp % 275;
  int d = threadIdx.x;             // 0..127
  int s, pp, qq, layer;
  decode_pos(pos, s, pp, qq, layer);
  const float* pc = pooled + b*Cin*275 + pos;
  const float* w = pw + (layer*DIM + d)*Cin;
  float acc = 0.f;
  #pragma unroll 4
  for (int c = 0; c < Cin; ++c) acc += pc[c*275] * w[c];
  acc += pb[layer*DIM + d];
  int ld = layer*DIM + d;
  float inv = g[ld] * rsqrtf(v[ld] + 1e-5f);
  acc = acc*inv + (bb[ld] - m[ld]*inv);
  pconv[bp*DIM + d] = fmaxf(acc, 0.f);
}

// ---------- assemble feat (B,L,1024): [x | broadcast(y0) | up5 | up9 | up13] ----------
__global__ __launch_bounds__(256) void feat_kernel(const float* __restrict__ x,
    const float* __restrict__ y0m, const float* __restrict__ pconv, float* __restrict__ feat) {
  int bl = blockIdx.x;             // b*256+l
  int b = bl >> 8, l = bl & 255;
  int h = l >> 4, w = l & 15;
  for (int c = threadIdx.x; c < DM; c += 256) {
    float val;
    if (c < Cin) {
      val = x[(b*Cin + c)*Lsp + l];
    } else if (c < Cin + DIM) {
      val = y0m[b*DIM + (c - Cin)];
    } else {
      int i = (c - (Cin+DIM)) >> 7;          // 0,1,2 -> s=5,9,13
      int d = (c - (Cin+DIM)) & 127;
      int s = (i==0) ? 5 : (i==1) ? 9 : 13;
      int off = (i==0) ? 0 : (i==1) ? 25 : 106;
      float scale = (float)s / 16.f;
      float sh = fmaxf((h + 0.5f)*scale - 0.5f, 0.f);
      int h0 = min((int)sh, s-1); float wh = sh - (float)h0; int h1 = min(h0+1, s-1);
      float sw = fmaxf((w + 0.5f)*scale - 0.5f, 0.f);
      int w0 = min((int)sw, s-1); float ww2 = sw - (float)w0; int w1 = min(w0+1, s-1);
      const float* pc = pconv + b*275*DIM;
      float v00 = pc[(off + h0*s + w0)*DIM + d];
      float v01 = pc[(off + h0*s + w1)*DIM + d];
      float v10 = pc[(off + h1*s + w0)*DIM + d];
      float v11 = pc[(off + h1*s + w1)*DIM + d];
      val = (1.f-wh)*((1.f-ww2)*v00 + ww2*v01) + wh*((1.f-ww2)*v10 + ww2*v11);
    }
    feat[bl*DM + c] = val;
  }
}

// ---------- generic fp32 GEMM: C[M][N] = A[M][Kd] * B[N][Kd]^T ----------
#define TS 64
#define KT 16
__global__ __launch_bounds__(256) void gemm_nt(const float* __restrict__ A,
    const float* __restrict__ B, float* __restrict__ C, int M, int N, int Kd) {
  __shared__ float As[KT][TS+1];
  __shared__ float Bs[KT][TS+1];
  int tid = threadIdx.x;
  int col0 = blockIdx.x * TS;
  int row0 = blockIdx.y * TS;
  int tx = tid & 15, ty = tid >> 4;
  float acc[4][4] = {};
  for (int k0 = 0; k0 < Kd; k0 += KT) {
    #pragma unroll
    for (int i = 0; i < 4; ++i) {
      int e = tid + 256*i;
      int r = e >> 4, kk = e & 15;
      As[kk][r] = A[(row0 + r)*Kd + k0 + kk];
      Bs[kk][r] = B[(col0 + r)*Kd + k0 + kk];
    }
    __syncthreads();
    #pragma unroll
    for (int kk = 0; kk < KT; ++kk) {
      float a[4], bvr[4];
      #pragma unroll
      for (int i = 0; i < 4; ++i) a[i] = As[kk][ty*4+i];
      #pragma unroll
      for (int j = 0; j < 4; ++j) bvr[j] = Bs[kk][tx*4+j];
      #pragma unroll
      for (int i = 0; i < 4; ++i)
        #pragma unroll
        for (int j = 0; j < 4; ++j)
          acc[i][j] += a[i]*bvr[j];
    }
    __syncthreads();
  }
  #pragma unroll
  for (int i = 0; i < 4; ++i)
    #pragma unroll
    for (int j = 0; j < 4; ++j)
      C[(row0 + ty*4 + i)*N + col0 + tx*4 + j] = acc[i][j];
}

// ---------- depthwise 3x3 conv + bias + silu; xz(B,L,4096) first half -> xcT(B,L,2048) ----------
__global__ __launch_bounds__(256) void dwconv_kernel(const float* __restrict__ xz,
    const float* __restrict__ cw, const float* __restrict__ cb, float* __restrict__ xcT) {
  int bl = blockIdx.x;
  int b = bl >> 8, l = bl & 255;
  int h = l >> 4, w = l & 15;
  const float* xzb = xz + (size_t)b*Lsp*(2*DI);
  for (int d = threadIdx.x; d < DI; d += 256) {
    float s = 0.f;
    #pragma unroll
    for (int dh = -1; dh <= 1; ++dh) {
      int hh = h + dh; if (hh < 0 || hh > 15) continue;
      #pragma unroll
      for (int dw = -1; dw <= 1; ++dw) {
        int ww2 = w + dw; if (ww2 < 0 || ww2 > 15) continue;
        s += xzb[(hh*16 + ww2)*(2*DI) + d] * cw[d*9 + (dh+1)*3 + (dw+1)];
      }
    }
    s += cb[d];
    xcT[((size_t)b*Lsp + l)*DI + d] = s / (1.f + __expf(-s));   // silu
  }
}

// scan-direction spatial index map
__device__ __forceinline__ int dir_map(int k, int l) {
  if (k == 0) return l;
  if (k == 1) return ((l & 15) << 4) | (l >> 4);
  if (k == 2) return 255 - l;
  int m = 255 - l; return ((m & 15) << 4) | (m >> 4);
}

// ---------- delta[b,k,l,d] = softplus(sum_r P[(b,sp),k*96+r]*dt_w[k,d,r] + dt_b[k,d]) ----------
__global__ __launch_bounds__(256) void delta_kernel(const float* __restrict__ P,
    const float* __restrict__ dtw, const float* __restrict__ dtb, float* __restrict__ delta) {
  int bk = blockIdx.x;             // b*4+k
  int b = bk >> 2, k = bk & 3;
  int d = blockIdx.y*256 + threadIdx.x;
  int l0 = blockIdx.z*64;
  const float* wr = dtw + ((size_t)k*DI + d)*RR;
  float w[RR];
  #pragma unroll
  for (int r = 0; r < RR; ++r) w[r] = wr[r];
  float bias = dtb[k*DI + d];
  float* out = delta + (size_t)bk*Lsp*DI;
  for (int l = l0; l < l0 + 64; ++l) {
    int sp = dir_map(k, l);
    const float* pr = P + (size_t)(b*Lsp + sp)*PW + k*96;
    float s = bias;
    #pragma unroll
    for (int r = 0; r < RR; ++r) s += pr[r] * w[r];
    out[l*DI + d] = (s > 20.f) ? s : log1pf(__expf(s));
  }
}

// ---------- selective scan: thread per (b,k,d), h[16] in registers ----------
__global__ __launch_bounds__(256) void scan_kernel(const float* __restrict__ delta,
    const float* __restrict__ xcT, const float* __restrict__ P,
    const float* __restrict__ A_logs, const float* __restrict__ Ds, float* __restrict__ out_y) {
  int bk = blockIdx.x;             // b*4+k
  int b = bk >> 2, k = bk & 3;
  int d = blockIdx.y*256 + threadIdx.x;
  float A[NST], h[NST];
  #pragma unroll
  for (int n = 0; n < NST; ++n) {
    A[n] = -__expf(A_logs[((size_t)k*DI + d)*NST + n]);
    h[n] = 0.f;
  }
  float Dv = Ds[k*DI + d];
  const float* del = delta + (size_t)bk*Lsp*DI;
  const float* xc  = xcT + (size_t)b*Lsp*DI;
  float* oy = out_y + (size_t)bk*Lsp*DI;
  for (int l = 0; l < Lsp; ++l) {
    int sp = dir_map(k, l);
    const float* pr = P + (size_t)(b*Lsp + sp)*PW + k*96;
    float dl = del[l*DI + d];
    float ul = xc[sp*DI + d];
    float du = dl * ul;
    float y = 0.f;
    #pragma unroll
    for (int n = 0; n < NST; ++n) {
      float Bn = pr[RR + n];
      float Cn = pr[RR + NST + n];
      h[n] = h[n]*__expf(dl*A[n]) + du*Bn;
      y += h[n]*Cn;
    }
    oy[l*DI + d] = y + Dv*ul;
  }
}

// ---------- combine 4 directions + LayerNorm + gate with silu(z) ----------
__global__ __launch_bounds__(256) void combine_ln_kernel(const float* __restrict__ out_y,
    const float* __restrict__ xz, const float* __restrict__ lng, const float* __restrict__ lnb,
    float* __restrict__ yg) {
  int bl = blockIdx.x;
  int b = bl >> 8, l = bl & 255;
  int h = l >> 4, w = l & 15;
  int lT = (w << 4) | h;
  const float* oy = out_y + (size_t)b*KK*Lsp*DI;
  float vals[8];
  float sum = 0.f, sumsq = 0.f;
  #pragma unroll
  for (int i = 0; i < 8; ++i) {
    int d = threadIdx.x + i*256;
    float yv = oy[(0*Lsp + l       )*DI + d]
             + oy[(2*Lsp + (255-l ))*DI + d]
             + oy[(1*Lsp + lT      )*DI + d]
             + oy[(3*Lsp + (255-lT))*DI + d];
    vals[i] = yv; sum += yv; sumsq += yv*yv;
  }
  __shared__ float r1[256], r2[256];
  r1[threadIdx.x] = sum; r2[threadIdx.x] = sumsq; __syncthreads();
  for (int off = 128; off > 0; off >>= 1) {
    if (threadIdx.x < off) { r1[threadIdx.x] += r1[threadIdx.x+off]; r2[threadIdx.x] += r2[threadIdx.x+off]; }
    __syncthreads();
  }
  float mu = r1[0] * (1.f/2048.f);
  float var = r2[0] * (1.f/2048.f) - mu*mu;
  float rstd = rsqrtf(var + 1e-5f);
  const float* zrow = xz + (size_t)bl*(2*DI) + DI;
  #pragma unroll
  for (int i = 0; i < 8; ++i) {
    int d = threadIdx.x + i*256;
    float z = zrow[d];
    float sz = z / (1.f + __expf(-z));
    yg[(size_t)bl*DI + d] = ((vals[i]-mu)*rstd*lng[d] + lnb[d]) * sz;
  }
}

// ---------- cbr epilogue: bias + BN + exact GELU, write NCHW ----------
__global__ void cbr_epilogue(const float* __restrict__ o2, const float* __restrict__ cb,
    const float* __restrict__ g, const float* __restrict__ beta, const float* __restrict__ m_,
    const float* __restrict__ v_, float* __restrict__ out) {
  int idx = blockIdx.x*256 + threadIdx.x;   // (b*128+dd)*256 + l
  int l = idx & 255;
  int rest = idx >> 8;
  int dd = rest & 127;
  int b = rest >> 7;
  float s = o2[((size_t)b*Lsp + l)*DIM + dd] + cb[dd];
  float inv = g[dd] * rsqrtf(v_[dd] + 1e-5f);
  s = s*inv + (beta[dd] - m_[dd]*inv);
  out[idx] = s * 0.5f * (1.f + erff(s * 0.70710678118f));
}

extern "C" void kernel_launch(void* const* d_in, const int* in_sizes, int n_in,
                              void* d_out, int out_size, void* d_ws, size_t ws_size,
                              hipStream_t stream) {
  const float* x        = (const float*)d_in[0];
  const float* pool_w   = (const float*)d_in[1];
  const float* pool_b   = (const float*)d_in[2];
  const float* bn_g     = (const float*)d_in[3];
  const float* bn_b     = (const float*)d_in[4];
  const float* bn_m     = (const float*)d_in[5];
  const float* bn_v     = (const float*)d_in[6];
  const float* in_proj_w= (const float*)d_in[7];
  const float* conv_w   = (const float*)d_in[8];
  const float* conv_b   = (const float*)d_in[9];
  const float* x_proj_w = (const float*)d_in[10];
  const float* dt_w     = (const float*)d_in[11];
  const float* dt_b     = (const float*)d_in[12];
  const float* A_logs   = (const float*)d_in[13];
  const float* Ds       = (const float*)d_in[14];
  const float* ln_g     = (const float*)d_in[15];
  const float* ln_b     = (const float*)d_in[16];
  const float* out_proj_w=(const float*)d_in[17];
  const float* cbr_w    = (const float*)d_in[18];
  const float* cbr_b    = (const float*)d_in[19];
  const float* cbr_g    = (const float*)d_in[20];
  const float* cbr_beta = (const float*)d_in[21];
  const float* cbr_m    = (const float*)d_in[22];
  const float* cbr_v    = (const float*)d_in[23];
  float* out = (float*)d_out;

  if (ws_size < (size_t)WS_FLOATS * sizeof(float)) return;  // not enough scratch
  float* ws = (float*)d_ws;
  float* feat   = ws + OFF_FEAT;
  float* pooled = ws + OFF_POOLED;
  float* pconv  = ws + OFF_PCONV;
  float* y0m    = ws + OFF_Y0M;
  float* xz     = ws + OFF_XZ;
  float* xcT    = ws + OFF_XCT;
  float* P      = ws + OFF_XDBL;
  float* delta  = ws + OFF_DELTA;
  float* out_y  = ws + OFF_OUTY;
  float* yg     = ws + OFF_YG;
  float* o1     = ws + OFF_O1;
  float* o2     = ws + OFF_O2;

  // stage A: pyramid pooling
  pool0_kernel<<<Bsz*DIM, 256, 0, stream>>>(x, pool_w, pool_b, bn_g, bn_b, bn_m, bn_v, y0m);
  pool_avg_kernel<<<Bsz*Cin, 288, 0, stream>>>(x, pooled);
  pconv_kernel<<<Bsz*275, 128, 0, stream>>>(pooled, pool_w, pool_b, bn_g, bn_b, bn_m, bn_v, pconv);
  feat_kernel<<<Bsz*Lsp, 256, 0, stream>>>(x, y0m, pconv, feat);

  // stage B: in_proj GEMM  (M=1024, N=4096, K=1024)
  gemm_nt<<<dim3(4096/TS, 1024/TS), 256, 0, stream>>>(feat, in_proj_w, xz, 1024, 4096, 1024);

  // stage C: depthwise conv + silu
  dwconv_kernel<<<Bsz*Lsp, 256, 0, stream>>>(xz, conv_w, conv_b, xcT);

  // stage D: x_proj as one GEMM: P[1024x384] = xcT[1024x2048] * x_proj_w[384x2048]^T
  gemm_nt<<<dim3(PW/TS, 1024/TS), 256, 0, stream>>>(xcT, x_proj_w, P, 1024, PW, 2048);

  // stage E: delta
  delta_kernel<<<dim3(Bsz*KK, DI/256, 4), 256, 0, stream>>>(P, dt_w, dt_b, delta);

  // stage F: selective scan
  scan_kernel<<<dim3(Bsz*KK, DI/256), 256, 0, stream>>>(delta, xcT, P, A_logs, Ds, out_y);

  // stage G: combine + LN + gate
  combine_ln_kernel<<<Bsz*Lsp, 256, 0, stream>>>(out_y, xz, ln_g, ln_b, yg);

  // stage H: out_proj GEMM (M=1024, N=1024, K=2048)
  gemm_nt<<<dim3(1024/TS, 1024/TS), 256, 0, stream>>>(yg, out_proj_w, o1, 1024, 1024, 2048);

  // stage I: cbr GEMM (M=1024, N=128, K=1024) + epilogue
  gemm_nt<<<dim3(DIM/TS, 1024/TS), 256, 0, stream>>>(o1, cbr_w, o2, 1024, DIM, 1024);
  cbr_epilogue<<<(Bsz*DIM*Lsp)/256, 256, 0, stream>>>(o2, cbr_b, cbr_g, cbr_beta, cbr_m, cbr_v, out);
}

// Round 3
// 439.557 us; speedup vs baseline: 2.7020x; 2.0268x over previous
//
#include <hip/hip_runtime.h>
#include <hip/hip_bf16.h>
#include <math.h>

// ---------- constants ----------
#define Bsz 4
#define Cin 512
#define Hh 16
#define Ww 16
#define Lsp 256
#define DIM 128
#define DM 1024      // dim*4 + 512
#define DI 2048
#define KK 4
#define NST 16
#define RR 64
#define PW 384       // K*96 projection rows

// ---------- ws layout (floats) ----------
#define OFF_FEAT    0u
#define SZ_FEAT     (Bsz*Lsp*DM)                 // 1048576
#define OFF_POOLED  (OFF_FEAT + SZ_FEAT)
#define SZ_POOLED   (Bsz*Cin*275)                // 563200
#define OFF_PCONV   (OFF_POOLED + SZ_POOLED)
#define SZ_PCONV    (Bsz*275*DIM)                // 140800
#define OFF_Y0M     (OFF_PCONV + SZ_PCONV)
#define SZ_Y0M      (Bsz*DIM)                    // 512
#define OFF_XZ      (OFF_Y0M + SZ_Y0M)
#define SZ_XZ       (Bsz*Lsp*2*DI)               // 4194304
#define OFF_XCT     (OFF_XZ + SZ_XZ)
#define SZ_XCT      (Bsz*Lsp*DI)                 // 2097152
#define OFF_XDBL    (OFF_XCT + SZ_XCT)
#define SZ_XDBL     (Bsz*Lsp*PW)                 // 393216  (P matrix, 1024x384)
#define OFF_DELTA   (OFF_XDBL + SZ_XDBL)
#define SZ_DELTA    (Bsz*KK*Lsp*DI)              // 8388608
#define OFF_OUTY    (OFF_DELTA + SZ_DELTA)
#define SZ_OUTY     (Bsz*KK*Lsp*DI)              // 8388608
#define OFF_YG      (OFF_OUTY + SZ_OUTY)
#define SZ_YG       (Bsz*Lsp*DI)                 // 2097152
#define OFF_O1      (OFF_YG + SZ_YG)
#define SZ_O1       (Bsz*Lsp*DM)                 // 1048576
#define OFF_O2      (OFF_O1 + SZ_O1)
#define SZ_O2       (Bsz*Lsp*DIM)                // 131072
#define WS_FLOATS   (OFF_O2 + SZ_O2)

typedef __attribute__((ext_vector_type(8))) short short8;
typedef __attribute__((ext_vector_type(4))) float f32x4;

__device__ __forceinline__ short f2bf(float x) {
  __hip_bfloat16 h = __float2bfloat16(x);
  short s;
  __builtin_memcpy(&s, &h, 2);
  return s;
}

// ---------- f32 -> bf16 bulk convert (n multiple of 8) ----------
__global__ __launch_bounds__(256) void f2bf_kernel(const float* __restrict__ in,
    short* __restrict__ out, int n) {
  int i = (blockIdx.x*256 + threadIdx.x)*8;
  if (i >= n) return;
  float4 a = *(const float4*)(in + i);
  float4 b = *(const float4*)(in + i + 4);
  short8 o;
  o[0]=f2bf(a.x); o[1]=f2bf(a.y); o[2]=f2bf(a.z); o[3]=f2bf(a.w);
  o[4]=f2bf(b.x); o[5]=f2bf(b.y); o[6]=f2bf(b.z); o[7]=f2bf(b.w);
  *(short8*)(out + i) = o;
}

// ---------- pool layer 0: conv1x1+BN+ReLU then global mean ----------
__global__ __launch_bounds__(256) void pool0_kernel(
    const float* __restrict__ x, const float* __restrict__ pw, const float* __restrict__ pb,
    const float* __restrict__ g, const float* __restrict__ bb,
    const float* __restrict__ m, const float* __restrict__ v, float* __restrict__ y0m) {
  int bd = blockIdx.x;             // b*128+d
  int b = bd >> 7, d = bd & 127;
  int l = threadIdx.x;
  const float* xb = x + (b*Cin)*Lsp + l;
  const float* w = pw + d*Cin;     // layer 0
  float s = 0.f;
  #pragma unroll 4
  for (int c = 0; c < Cin; ++c) s += xb[c*Lsp] * w[c];
  s += pb[d];
  float inv = g[d] * rsqrtf(v[d] + 1e-5f);
  s = s*inv + (bb[d] - m[d]*inv);
  s = fmaxf(s, 0.f);
  __shared__ float red[256];
  red[l] = s; __syncthreads();
  for (int off = 128; off > 0; off >>= 1) {
    if (l < off) red[l] += red[l+off];
    __syncthreads();
  }
  if (l == 0) y0m[bd] = red[0] * (1.f/256.f);
}

// ---------- adaptive avg pool of x to 5x5,9x9,13x13 (concatenated 275 positions) ----------
__device__ __forceinline__ void decode_pos(int pos, int& s, int& pp, int& qq, int& layer) {
  if (pos < 25)       { s = 5;  layer = 1; int t = pos;       pp = t/5;  qq = t%5;  }
  else if (pos < 106) { s = 9;  layer = 2; int t = pos - 25;  pp = t/9;  qq = t%9;  }
  else                { s = 13; layer = 3; int t = pos - 106; pp = t/13; qq = t%13; }
}

__global__ void pool_avg_kernel(const float* __restrict__ x, float* __restrict__ pooled) {
  int bc = blockIdx.x;             // b*512+c
  int pos = threadIdx.x;
  if (pos >= 275) return;
  int s, pp, qq, layer;
  decode_pos(pos, s, pp, qq, layer);
  int hs = (pp*Hh)/s, he = ((pp+1)*Hh + s-1)/s;
  int ws = (qq*Ww)/s, we = ((qq+1)*Ww + s-1)/s;
  const float* xb = x + bc*Lsp;
  float acc = 0.f;
  for (int hh = hs; hh < he; ++hh)
    for (int ww2 = ws; ww2 < we; ++ww2)
      acc += xb[hh*Ww + ww2];
  pooled[bc*275 + pos] = acc / (float)((he-hs)*(we-ws));
}

// ---------- conv1x1 + BN + ReLU on pooled features ----------
__global__ void pconv_kernel(const float* __restrict__ pooled, const float* __restrict__ pw,
    const float* __restrict__ pb, const float* __restrict__ g, const float* __restrict__ bb,
    const float* __restrict__ m, const float* __restrict__ v, float* __restrict__ pconv) {
  int bp = blockIdx.x;             // b*275+pos
  int b = bp / 275, pos = bp % 275;
  int d = threadIdx.x;             // 0..127
  int s, pp, qq, layer;
  decode_pos(pos, s, pp, qq, layer);
  const float* pc = pooled + b*Cin*275 + pos;
  const float* w = pw + (layer*DIM + d)*Cin;
  float acc = 0.f;
  #pragma unroll 4
  for (int c = 0; c < Cin; ++c) acc += pc[c*275] * w[c];
  acc += pb[layer*DIM + d];
  int ld = layer*DIM + d;
  float inv = g[ld] * rsqrtf(v[ld] + 1e-5f);
  acc = acc*inv + (bb[ld] - m[ld]*inv);
  pconv[bp*DIM + d] = fmaxf(acc, 0.f);
}

// ---------- assemble feat (B,L,1024) in bf16 ----------
__global__ __launch_bounds__(256) void feat_kernel(const float* __restrict__ x,
    const float* __restrict__ y0m, const float* __restrict__ pconv, short* __restrict__ featB) {
  int bl = blockIdx.x;             // b*256+l
  int b = bl >> 8, l = bl & 255;
  int h = l >> 4, w = l & 15;
  for (int c = threadIdx.x; c < DM; c += 256) {
    float val;
    if (c < Cin) {
      val = x[(b*Cin + c)*Lsp + l];
    } else if (c < Cin + DIM) {
      val = y0m[b*DIM + (c - Cin)];
    } else {
      int i = (c - (Cin+DIM)) >> 7;          // 0,1,2 -> s=5,9,13
      int d = (c - (Cin+DIM)) & 127;
      int s = (i==0) ? 5 : (i==1) ? 9 : 13;
      int off = (i==0) ? 0 : (i==1) ? 25 : 106;
      float scale = (float)s / 16.f;
      float sh = fmaxf((h + 0.5f)*scale - 0.5f, 0.f);
      int h0 = min((int)sh, s-1); float wh = sh - (float)h0; int h1 = min(h0+1, s-1);
      float sw = fmaxf((w + 0.5f)*scale - 0.5f, 0.f);
      int w0 = min((int)sw, s-1); float ww2 = sw - (float)w0; int w1 = min(w0+1, s-1);
      const float* pc = pconv + b*275*DIM;
      float v00 = pc[(off + h0*s + w0)*DIM + d];
      float v01 = pc[(off + h0*s + w1)*DIM + d];
      float v10 = pc[(off + h1*s + w0)*DIM + d];
      float v11 = pc[(off + h1*s + w1)*DIM + d];
      val = (1.f-wh)*((1.f-ww2)*v00 + ww2*v01) + wh*((1.f-ww2)*v10 + ww2*v11);
    }
    featB[bl*DM + c] = f2bf(val);
  }
}

// ---------- bf16 MFMA GEMM: C[M][N] = A[M][K] * B[N][K]^T ----------
// 128x128 tile, BK=64, 4 waves (2x2), 4x4 16x16x32 frags per wave.
// LDS staged via global_load_lds (linear dest) with XOR-swizzled global source,
// swizzled ds_read (rule #21: both-sides swizzle).
__device__ __forceinline__ void gload_lds16(const short* g, short* l) {
  __builtin_amdgcn_global_load_lds((const __attribute__((address_space(1))) void*)g,
                                   (__attribute__((address_space(3))) void*)l, 16, 0, 0);
}

template<int OUTBF>
__global__ __launch_bounds__(256) void gemm_bf(const short* __restrict__ Ag,
    const short* __restrict__ Bg, void* __restrict__ Cout, int M, int N, int K) {
  __shared__ short Als[128*64];
  __shared__ short Bls[128*64];
  int tid = threadIdx.x;
  int w = tid >> 6, lane = tid & 63;
  int wm = w >> 1, wn = w & 1;
  int row0 = blockIdx.y * 128, col0 = blockIdx.x * 128;
  f32x4 acc[4][4];
  #pragma unroll
  for (int i = 0; i < 4; ++i)
    #pragma unroll
    for (int j = 0; j < 4; ++j)
      acc[i][j] = (f32x4){0.f, 0.f, 0.f, 0.f};

  for (int k0 = 0; k0 < K; k0 += 64) {
    #pragma unroll
    for (int i = 0; i < 4; ++i) {
      int slot = i*256 + w*64 + lane;
      int r = slot >> 3, pc = slot & 7;
      int c = pc ^ (r & 7);                       // logical 16B-chunk for this slot
      gload_lds16(Ag + (size_t)(row0 + r)*K + k0 + c*8, &Als[(i*256 + w*64)*8]);
      gload_lds16(Bg + (size_t)(col0 + r)*K + k0 + c*8, &Bls[(i*256 + w*64)*8]);
    }
    __syncthreads();
    #pragma unroll
    for (int ks = 0; ks < 2; ++ks) {
      short8 af[4], bfr[4];
      int rsel = lane & 15, csel = ks*4 + (lane >> 4);
      #pragma unroll
      for (int mi = 0; mi < 4; ++mi) {
        int row = wm*64 + mi*16 + rsel;
        af[mi] = *(const short8*)&Als[row*64 + ((csel ^ (row & 7)) << 3)];
      }
      #pragma unroll
      for (int ni = 0; ni < 4; ++ni) {
        int row = wn*64 + ni*16 + rsel;
        bfr[ni] = *(const short8*)&Bls[row*64 + ((csel ^ (row & 7)) << 3)];
      }
      #pragma unroll
      for (int mi = 0; mi < 4; ++mi)
        #pragma unroll
        for (int ni = 0; ni < 4; ++ni)
          acc[mi][ni] = __builtin_amdgcn_mfma_f32_16x16x32_bf16(af[mi], bfr[ni], acc[mi][ni], 0, 0, 0);
    }
    __syncthreads();
  }
  // epilogue: D row = (lane>>4)*4 + j, col = lane&15
  #pragma unroll
  for (int mi = 0; mi < 4; ++mi) {
    int rbase = row0 + wm*64 + mi*16 + ((lane >> 4) << 2);
    #pragma unroll
    for (int ni = 0; ni < 4; ++ni) {
      int colg = col0 + wn*64 + ni*16 + (lane & 15);
      #pragma unroll
      for (int j = 0; j < 4; ++j) {
        if (OUTBF) ((short*)Cout)[(size_t)(rbase + j)*N + colg] = f2bf(acc[mi][ni][j]);
        else       ((float*)Cout)[(size_t)(rbase + j)*N + colg] = acc[mi][ni][j];
      }
    }
  }
}

// ---------- depthwise 3x3 conv + bias + silu -> xcT (f32, for scan) + xcB (bf16, for xproj GEMM) ----------
__global__ __launch_bounds__(256) void dwconv_kernel(const float* __restrict__ xz,
    const float* __restrict__ cw, const float* __restrict__ cb,
    float* __restrict__ xcT, short* __restrict__ xcB) {
  int bl = blockIdx.x;
  int b = bl >> 8, l = bl & 255;
  int h = l >> 4, w = l & 15;
  const float* xzb = xz + (size_t)b*Lsp*(2*DI);
  for (int d = threadIdx.x; d < DI; d += 256) {
    float s = 0.f;
    #pragma unroll
    for (int dh = -1; dh <= 1; ++dh) {
      int hh = h + dh; if (hh < 0 || hh > 15) continue;
      #pragma unroll
      for (int dw = -1; dw <= 1; ++dw) {
        int ww2 = w + dw; if (ww2 < 0 || ww2 > 15) continue;
        s += xzb[(hh*16 + ww2)*(2*DI) + d] * cw[d*9 + (dh+1)*3 + (dw+1)];
      }
    }
    s += cb[d];
    float r = s / (1.f + __expf(-s));   // silu
    xcT[((size_t)b*Lsp + l)*DI + d] = r;
    xcB[((size_t)b*Lsp + l)*DI + d] = f2bf(r);
  }
}

// scan-direction spatial index map
__device__ __forceinline__ int dir_map(int k, int l) {
  if (k == 0) return l;
  if (k == 1) return ((l & 15) << 4) | (l >> 4);
  if (k == 2) return 255 - l;
  int m = 255 - l; return ((m & 15) << 4) | (m >> 4);
}

// ---------- delta[b,k,l,d] = softplus(sum_r P[(b,sp),k*96+r]*dt_w[k,d,r] + dt_b[k,d]) ----------
__global__ __launch_bounds__(256) void delta_kernel(const float* __restrict__ P,
    const float* __restrict__ dtw, const float* __restrict__ dtb, float* __restrict__ delta) {
  int bk = blockIdx.x;             // b*4+k
  int b = bk >> 2, k = bk & 3;
  int d = blockIdx.y*256 + threadIdx.x;
  int l0 = blockIdx.z*64;
  const float* wr = dtw + ((size_t)k*DI + d)*RR;
  float w[RR];
  #pragma unroll
  for (int r = 0; r < RR; ++r) w[r] = wr[r];
  float bias = dtb[k*DI + d];
  float* out = delta + (size_t)bk*Lsp*DI;
  for (int l = l0; l < l0 + 64; ++l) {
    int sp = dir_map(k, l);
    const float* pr = P + (size_t)(b*Lsp + sp)*PW + k*96;
    float s = bias;
    #pragma unroll
    for (int r = 0; r < RR; ++r) s += pr[r] * w[r];
    out[l*DI + d] = (s > 20.f) ? s : log1pf(__expf(s));
  }
}

// ---------- selective scan: 4 threads per d (4 states each), shfl-reduce y ----------
__global__ __launch_bounds__(256) void scan_kernel(const float* __restrict__ delta,
    const float* __restrict__ xcT, const float* __restrict__ P,
    const float* __restrict__ A_logs, const float* __restrict__ Ds, float* __restrict__ out_y) {
  int bk = blockIdx.x;             // b*4+k
  int b = bk >> 2, k = bk & 3;
  int tid = threadIdx.x;
  int wv = tid >> 6, lane = tid & 63;
  int dloc = lane >> 2;            // 0..15
  int ng = lane & 3;               // state group 0..3
  int d = blockIdx.y*64 + wv*16 + dloc;
  int n0 = ng*4;
  float A[4], h[4] = {0.f, 0.f, 0.f, 0.f};
  #pragma unroll
  for (int j = 0; j < 4; ++j)
    A[j] = -__expf(A_logs[((size_t)k*DI + d)*NST + n0 + j]);
  float Dv = Ds[k*DI + d];
  const float* del = delta + (size_t)bk*Lsp*DI;
  const float* xc  = xcT + (size_t)b*Lsp*DI;
  float* oy = out_y + (size_t)bk*Lsp*DI;
  for (int l = 0; l < Lsp; ++l) {
    int sp = dir_map(k, l);
    const float* pr = P + (size_t)(b*Lsp + sp)*PW + k*96;
    float dl = del[l*DI + d];
    float ul = xc[sp*DI + d];
    float du = dl * ul;
    float y = 0.f;
    #pragma unroll
    for (int j = 0; j < 4; ++j) {
      h[j] = h[j]*__expf(dl*A[j]) + du*pr[RR + n0 + j];
      y += h[j]*pr[RR + NST + n0 + j];
    }
    y += __shfl_xor(y, 1);
    y += __shfl_xor(y, 2);
    if (ng == 0) oy[l*DI + d] = y + Dv*ul;
  }
}

// ---------- combine 4 directions + LayerNorm + gate with silu(z) -> bf16 ----------
__global__ __launch_bounds__(256) void combine_ln_kernel(const float* __restrict__ out_y,
    const float* __restrict__ xz, const float* __restrict__ lng, const float* __restrict__ lnb,
    short* __restrict__ ygB) {
  int bl = blockIdx.x;
  int b = bl >> 8, l = bl & 255;
  int h = l >> 4, w = l & 15;
  int lT = (w << 4) | h;
  const float* oy = out_y + (size_t)b*KK*Lsp*DI;
  float vals[8];
  float sum = 0.f, sumsq = 0.f;
  #pragma unroll
  for (int i = 0; i < 8; ++i) {
    int d = threadIdx.x + i*256;
    float yv = oy[(0*Lsp + l       )*DI + d]
             + oy[(2*Lsp + (255-l ))*DI + d]
             + oy[(1*Lsp + lT      )*DI + d]
             + oy[(3*Lsp + (255-lT))*DI + d];
    vals[i] = yv; sum += yv; sumsq += yv*yv;
  }
  __shared__ float r1[256], r2[256];
  r1[threadIdx.x] = sum; r2[threadIdx.x] = sumsq; __syncthreads();
  for (int off = 128; off > 0; off >>= 1) {
    if (threadIdx.x < off) { r1[threadIdx.x] += r1[threadIdx.x+off]; r2[threadIdx.x] += r2[threadIdx.x+off]; }
    __syncthreads();
  }
  float mu = r1[0] * (1.f/2048.f);
  float var = r2[0] * (1.f/2048.f) - mu*mu;
  float rstd = rsqrtf(var + 1e-5f);
  const float* zrow = xz + (size_t)bl*(2*DI) + DI;
  #pragma unroll
  for (int i = 0; i < 8; ++i) {
    int d = threadIdx.x + i*256;
    float z = zrow[d];
    float sz = z / (1.f + __expf(-z));
    ygB[(size_t)bl*DI + d] = f2bf(((vals[i]-mu)*rstd*lng[d] + lnb[d]) * sz);
  }
}

// ---------- cbr epilogue: bias + BN + exact GELU, write NCHW ----------
__global__ void cbr_epilogue(const float* __restrict__ o2, const float* __restrict__ cb,
    const float* __restrict__ g, const float* __restrict__ beta, const float* __restrict__ m_,
    const float* __restrict__ v_, float* __restrict__ out) {
  int idx = blockIdx.x*256 + threadIdx.x;   // (b*128+dd)*256 + l
  int l = idx & 255;
  int rest = idx >> 8;
  int dd = rest & 127;
  int b = rest >> 7;
  float s = o2[((size_t)b*Lsp + l)*DIM + dd] + cb[dd];
  float inv = g[dd] * rsqrtf(v_[dd] + 1e-5f);
  s = s*inv + (beta[dd] - m_[dd]*inv);
  out[idx] = s * 0.5f * (1.f + erff(s * 0.70710678118f));
}

extern "C" void kernel_launch(void* const* d_in, const int* in_sizes, int n_in,
                              void* d_out, int out_size, void* d_ws, size_t ws_size,
                              hipStream_t stream) {
  const float* x        = (const float*)d_in[0];
  const float* pool_w   = (const float*)d_in[1];
  const float* pool_b   = (const float*)d_in[2];
  const float* bn_g     = (const float*)d_in[3];
  const float* bn_b     = (const float*)d_in[4];
  const float* bn_m     = (const float*)d_in[5];
  const float* bn_v     = (const float*)d_in[6];
  const float* in_proj_w= (const float*)d_in[7];
  const float* conv_w   = (const float*)d_in[8];
  const float* conv_b   = (const float*)d_in[9];
  const float* x_proj_w = (const float*)d_in[10];
  const float* dt_w     = (const float*)d_in[11];
  const float* dt_b     = (const float*)d_in[12];
  const float* A_logs   = (const float*)d_in[13];
  const float* Ds       = (const float*)d_in[14];
  const float* ln_g     = (const float*)d_in[15];
  const float* ln_b     = (const float*)d_in[16];
  const float* out_proj_w=(const float*)d_in[17];
  const float* cbr_w    = (const float*)d_in[18];
  const float* cbr_b    = (const float*)d_in[19];
  const float* cbr_g    = (const float*)d_in[20];
  const float* cbr_beta = (const float*)d_in[21];
  const float* cbr_m    = (const float*)d_in[22];
  const float* cbr_v    = (const float*)d_in[23];
  float* out = (float*)d_out;

  if (ws_size < (size_t)WS_FLOATS * sizeof(float)) return;  // not enough scratch
  float* ws = (float*)d_ws;
  float* pooled = ws + OFF_POOLED;
  float* pconv  = ws + OFF_PCONV;
  float* y0m    = ws + OFF_Y0M;
  float* xz     = ws + OFF_XZ;
  float* xcT    = ws + OFF_XCT;
  float* P      = ws + OFF_XDBL;
  float* delta  = ws + OFF_DELTA;
  float* out_y  = ws + OFF_OUTY;
  float* o2     = ws + OFF_O2;

  // bf16 overlays (lifetimes verified against the stage timeline):
  short* featB = (short*)(ws + OFF_POOLED);              // written end of stage A (pooled dead), read stage B
  short* wInB  = (short*)(ws + OFF_DELTA);               // read at B; delta written at E (after B)
  short* wXB   = (short*)(ws + OFF_DELTA) + 4194304;     // read at D; delta written at E (after D)
  short* wOB   = (short*)(ws + OFF_FEAT);                // feat region unused otherwise; read at H
  short* wCB   = (short*)(ws + OFF_PCONV);               // written after feat_kernel (pconv dead), read at I
  short* xcB   = (short*)(ws + OFF_OUTY);                // written C, read D; out_y written F (after D)
  short* ygB   = (short*)(ws + OFF_DELTA);               // written G (delta dead after F), read H
  short* o1B   = (short*)(ws + OFF_O1);                  // written H, read I

  // stage A: pyramid pooling
  pool0_kernel<<<Bsz*DIM, 256, 0, stream>>>(x, pool_w, pool_b, bn_g, bn_b, bn_m, bn_v, y0m);
  pool_avg_kernel<<<Bsz*Cin, 288, 0, stream>>>(x, pooled);
  pconv_kernel<<<Bsz*275, 128, 0, stream>>>(pooled, pool_w, pool_b, bn_g, bn_b, bn_m, bn_v, pconv);
  feat_kernel<<<Bsz*Lsp, 256, 0, stream>>>(x, y0m, pconv, featB);

  // weight conversions (after stage A so overlaid regions are dead)
  f2bf_kernel<<<(4096*1024)/2048, 256, 0, stream>>>(in_proj_w, wInB, 4096*1024);
  f2bf_kernel<<<(PW*2048)/2048,   256, 0, stream>>>(x_proj_w,  wXB,  PW*2048);
  f2bf_kernel<<<(1024*2048)/2048, 256, 0, stream>>>(out_proj_w, wOB, 1024*2048);
  f2bf_kernel<<<(DIM*1024)/2048,  256, 0, stream>>>(cbr_w,      wCB, DIM*1024);

  // stage B: in_proj GEMM (M=1024, N=4096, K=1024), f32 out
  gemm_bf<0><<<dim3(4096/128, 1024/128), 256, 0, stream>>>(featB, wInB, xz, 1024, 4096, 1024);

  // stage C: depthwise conv + silu
  dwconv_kernel<<<Bsz*Lsp, 256, 0, stream>>>(xz, conv_w, conv_b, xcT, xcB);

  // stage D: x_proj GEMM: P[1024x384] = xcB * wXB^T (K=2048), f32 out
  gemm_bf<0><<<dim3(PW/128, 1024/128), 256, 0, stream>>>(xcB, wXB, P, 1024, PW, 2048);

  // stage E: delta
  delta_kernel<<<dim3(Bsz*KK, DI/256, 4), 256, 0, stream>>>(P, dt_w, dt_b, delta);

  // stage F: selective scan (4 threads/d over 16 states)
  scan_kernel<<<dim3(Bsz*KK, DI/64), 256, 0, stream>>>(delta, xcT, P, A_logs, Ds, out_y);

  // stage G: combine + LN + gate -> bf16
  combine_ln_kernel<<<Bsz*Lsp, 256, 0, stream>>>(out_y, xz, ln_g, ln_b, ygB);

  // stage H: out_proj GEMM (M=1024, N=1024, K=2048), bf16 out
  gemm_bf<1><<<dim3(1024/128, 1024/128), 256, 0, stream>>>(ygB, wOB, o1B, 1024, 1024, 2048);

  // stage I: cbr GEMM (M=1024, N=128, K=1024), f32 out + epilogue
  gemm_bf<0><<<dim3(DIM/128, 1024/128), 256, 0, stream>>>(o1B, wCB, o2, 1024, DIM, 1024);
  cbr_epilogue<<<(Bsz*DIM*Lsp)/256, 256, 0, stream>>>(o2, cbr_b, cbr_g, cbr_beta, cbr_m, cbr_v, out);
}